// Round 7
// baseline (246.867 us; speedup 1.0000x reference)
//
#include <hip/hip_runtime.h>
#include <math.h>

#define N_NODES 100000
#define NG 100
#define N_PER 1000
#define N_EDGES 3200000
#define EPG 32000
#define EPG4 8000
#define CSTRIDE 88          // fixed CSR row stride (shorts); P(deg>=88) ~ 5e-15
#define K_TOP 800
#define F_IN 128
#define F_MID 16
#define F_OUT 256
#define SENT 1000
#define GEMM_ROWS 256
#define GEMM_BLOCKS ((N_NODES + GEMM_ROWS - 1) / GEMM_ROWS)

typedef __attribute__((ext_vector_type(8))) short short8;
typedef __attribute__((ext_vector_type(4))) float floatx4;

__device__ __forceinline__ unsigned short f2bf(float x) {
    union { float f; unsigned int u; } c; c.f = x;
    unsigned int u = c.u;
    u = u + 0x7FFF + ((u >> 16) & 1);
    return (unsigned short)(u >> 16);
}
__device__ __forceinline__ float bf2f(unsigned short h) {
    return __uint_as_float(((unsigned int)h) << 16);
}
__device__ __forceinline__ void add4(float4& a, const float4 b) {
    a.x += b.x; a.y += b.y; a.z += b.z; a.w += b.w;
}
__device__ __forceinline__ int fidx4(int s, int l) {   // bank-conflict swizzle
    return s * 16 + ((4 * (l + ((s >> 1) & 3))) & 15);
}
__device__ __forceinline__ unsigned int fkey(float f) {  // order-preserving asc
    unsigned int u = __float_as_uint(f);
    return (u & 0x80000000u) ? ~u : (u | 0x80000000u);
}
__device__ __forceinline__ float unfkey(unsigned int k) {
    return __uint_as_float((k & 0x80000000u) ? (k & 0x7FFFFFFFu) : ~k);
}

// ============ kernel 1: CSR blocks (single pass, fixed stride) + MFMA GEMM1 ============
__global__ __launch_bounds__(1024) void k_front(const float* __restrict__ x,
    const float* __restrict__ W1, const int* __restrict__ ei,
    unsigned short* __restrict__ csr, int* __restrict__ cntG,
    float* __restrict__ dis1G, float* __restrict__ xw1)
{
    __shared__ __align__(16) char smem[8448];
    int b = blockIdx.x, t = threadIdx.x;
    if (b < NG) {
        // ---- CSR build: one edge pass, LDS cursor atomics, direct scatter ----
        int* cur = (int*)smem;   // 1000 ints
        int g = b, ebase = g * EPG, nbase = g * N_PER;
        unsigned short* cg = csr + (size_t)g * (N_PER * CSTRIDE);
        if (t < N_PER) cur[t] = 0;
        __syncthreads();
        const int4* dst4 = (const int4*)(ei + N_EDGES + ebase);
        const int4* src4 = (const int4*)(ei + ebase);
        for (int i = t; i < EPG4; i += 1024) {
            int4 s4 = src4[i]; int4 d4 = dst4[i];
            int dl, p;
            dl = d4.x - nbase; p = atomicAdd(&cur[dl], 1); if (p < CSTRIDE) cg[dl * CSTRIDE + p] = (unsigned short)(s4.x - nbase);
            dl = d4.y - nbase; p = atomicAdd(&cur[dl], 1); if (p < CSTRIDE) cg[dl * CSTRIDE + p] = (unsigned short)(s4.y - nbase);
            dl = d4.z - nbase; p = atomicAdd(&cur[dl], 1); if (p < CSTRIDE) cg[dl * CSTRIDE + p] = (unsigned short)(s4.z - nbase);
            dl = d4.w - nbase; p = atomicAdd(&cur[dl], 1); if (p < CSTRIDE) cg[dl * CSTRIDE + p] = (unsigned short)(s4.w - nbase);
        }
        __syncthreads();
        if (t < N_PER) {
            int c = cur[t]; if (c > CSTRIDE) c = CSTRIDE;
            int c8 = (c + 7) & ~7; if (c8 > CSTRIDE) c8 = CSTRIDE;
            cntG[nbase + t] = c;
            dis1G[nbase + t] = rsqrtf((float)cur[t] + 1.0f);
            for (int q = c; q < c8; q++) cg[t * CSTRIDE + q] = (unsigned short)SENT;
        }
    } else {
        // ---- GEMM1 tile: 256 rows, MFMA bf16x3 split ----
        unsigned short* bTh = (unsigned short*)smem;          // [16][128]
        unsigned short* bTl = (unsigned short*)(smem + 4096); // [16][128]
        for (int i = t; i < F_IN * F_MID; i += 1024) {
            int k = i >> 4, n = i & 15;
            float w = W1[i];
            unsigned short hh = f2bf(w);
            bTh[n * 128 + k] = hh;
            bTl[n * 128 + k] = f2bf(w - bf2f(hh));
        }
        __syncthreads();
        int wave = t >> 6, lane = t & 63;
        int m = lane & 15, q = lane >> 4;
        long rbase = (long)(b - NG) * GEMM_ROWS + wave * 16;
        long arow = rbase + m;
        const float* xr = x + ((arow < N_NODES) ? arow : (N_NODES - 1)) * F_IN;
        short8 ah[4], al[4], bh[4], bl[4];
#pragma unroll
        for (int c = 0; c < 4; c++) {
            float4 v0 = *(const float4*)(xr + 32 * c + 8 * q);
            float4 v1 = *(const float4*)(xr + 32 * c + 8 * q + 4);
            float vv[8] = {v0.x, v0.y, v0.z, v0.w, v1.x, v1.y, v1.z, v1.w};
            short8 h8, l8;
#pragma unroll
            for (int i = 0; i < 8; i++) {
                unsigned short hh = f2bf(vv[i]);
                h8[i] = (short)hh;
                l8[i] = (short)f2bf(vv[i] - bf2f(hh));
            }
            ah[c] = h8; al[c] = l8;
            bh[c] = *(const short8*)(bTh + m * 128 + 32 * c + 8 * q);
            bl[c] = *(const short8*)(bTl + m * 128 + 32 * c + 8 * q);
        }
        floatx4 acc = {0.f, 0.f, 0.f, 0.f};
#pragma unroll
        for (int c = 0; c < 4; c++) {
            acc = __builtin_amdgcn_mfma_f32_16x16x32_bf16(ah[c], bh[c], acc, 0, 0, 0);
            acc = __builtin_amdgcn_mfma_f32_16x16x32_bf16(al[c], bh[c], acc, 0, 0, 0);
            acc = __builtin_amdgcn_mfma_f32_16x16x32_bf16(ah[c], bl[c], acc, 0, 0, 0);
        }
#pragma unroll
        for (int r = 0; r < 4; r++) {
            long orow = rbase + q * 4 + r;
            if (orow < N_NODES) xw1[orow * F_MID + m] = acc[r];
        }
    }
}

// ============ kernel 2: per-graph phases, sorted-node gathers ============
__global__ __launch_bounds__(1024) void k_mega(const unsigned short* __restrict__ csr,
    const int* __restrict__ cntG, const float* __restrict__ dis1G,
    const float* __restrict__ xw1,
    const float* __restrict__ b1, const float* __restrict__ w_rel,
    const float* __restrict__ b_rel, const float* __restrict__ w_root,
    const float* __restrict__ W2, const float* __restrict__ b2,
    float* __restrict__ out)
{
    __shared__ __align__(16) float feat[(N_PER + 1) * F_MID];
    __shared__ __align__(16) unsigned short fbf[N_PER * F_MID];
    __shared__ __align__(16) unsigned short w2t[F_OUT * F_MID];
    __shared__ float sc[N_PER];
    __shared__ float msk[N_PER + 1];
    __shared__ float wsrc[N_PER + 1];
    __shared__ float hw[N_PER + 1];
    __shared__ float hro[N_PER];
    __shared__ float dis2a[N_PER];
    __shared__ float dis1l[N_PER];
    __shared__ int cnt8l[N_PER];
    __shared__ unsigned short sn[N_PER];   // nodes sorted by c8
    __shared__ int bbase[16], bcur[16];
    __shared__ int hist[1024];
    __shared__ float partial[F_OUT];
    __shared__ int wtot[16], wexc[16];
    __shared__ unsigned int tiebits[32];
    __shared__ int sh_b1, sh_r1, sh_len, sh_cntgt;
    __shared__ float sh_thr;

    int t = threadIdx.x, g = blockIdx.x;
    int nbase = g * N_PER;
    const unsigned short* cg = csr + (size_t)g * (N_PER * CSTRIDE);
    int grp = t >> 2, l = t & 3;
    int lane = t & 63, wid = t >> 6;

    if (t < 16) bbase[t] = 0;
    if (t == 0) { sh_cntgt = 0; sh_len = 0; }
    if (t < 32) tiebits[t] = 0;
    __syncthreads();
    int myc8 = 0;
    if (t < N_PER) {
        int c = cntG[nbase + t];
        myc8 = (c + 7) & ~7; if (myc8 > CSTRIDE) myc8 = CSTRIDE;
        cnt8l[t] = myc8;
        dis1l[t] = dis1G[nbase + t];
        atomicAdd(&bbase[myc8 >> 3], 1);
    }
    for (int i = t; i < F_OUT * F_MID; i += 1024) {
        int f = i >> 4, jj = i & 15;
        w2t[i] = f2bf(W2[jj * F_OUT + f]);
    }
    __syncthreads();
    if (t == 0) {
        int acc = 0;
        for (int i = 0; i < 16; i++) { int c = bbase[i]; bbase[i] = acc; bcur[i] = acc; acc += c; }
    }
    __syncthreads();
    if (t < N_PER) { int p = atomicAdd(&bcur[myc8 >> 3], 1); sn[p] = (unsigned short)t; }

    // ---- stage feat = xw1 * dis1 (swizzled); sentinel row zero ----
    {
        const float4* xsrc = (const float4*)(xw1 + (size_t)nbase * F_MID);
        for (int i = t; i < N_PER * 4; i += 1024) {
            int n = i >> 2, q = i & 3;
            float4 v = xsrc[i];
            float d = dis1l[n];
            v.x *= d; v.y *= d; v.z *= d; v.w *= d;
            *(float4*)(feat + fidx4(n, q)) = v;
        }
        if (t < 4) { float4 z = {0.f, 0.f, 0.f, 0.f}; *(float4*)(feat + fidx4(SENT, t)) = z; }
        if (t == 0) { hw[SENT] = 0.f; msk[SENT] = 0.f; wsrc[SENT] = 0.f; }
    }
    __syncthreads();

    float4 b14 = *(const float4*)(b1 + 4 * l);
    float4 wr4 = *(const float4*)(w_rel + 4 * l);
    float4 wo4 = *(const float4*)(w_root + 4 * l);
    float brel = b_rel[0];

    // ---- conv1 aggregation + relu -> hreg; fused hw/hro readout ----
    float4 hreg[4];
    int nidx[4];
#pragma unroll
    for (int rr = 0; rr < 4; rr++) {
        int pos = grp + 256 * rr;
        nidx[rr] = -1;
        if (pos < N_PER) {
            int n = sn[pos]; nidx[rr] = n;
            int c8 = cnt8l[n];
            const unsigned short* cp = cg + n * CSTRIDE;
            float4 a0 = {0,0,0,0}, a1 = a0, a2 = a0, a3 = a0;
            for (int k = 0; k < c8; k += 4) {
                uint2 wv = *(const uint2*)(cp + k);
                add4(a0, *(const float4*)(feat + fidx4((int)(wv.x & 0xFFFF), l)));
                add4(a1, *(const float4*)(feat + fidx4((int)(wv.x >> 16), l)));
                add4(a2, *(const float4*)(feat + fidx4((int)(wv.y & 0xFFFF), l)));
                add4(a3, *(const float4*)(feat + fidx4((int)(wv.y >> 16), l)));
            }
            add4(a0, a1); add4(a2, a3); add4(a0, a2);
            float4 sf = *(const float4*)(feat + fidx4(n, l));
            float di = dis1l[n];
            float4 hv;
            hv.x = fmaxf(fmaf(di, a0.x + sf.x, b14.x), 0.f);
            hv.y = fmaxf(fmaf(di, a0.y + sf.y, b14.y), 0.f);
            hv.z = fmaxf(fmaf(di, a0.z + sf.z, b14.z), 0.f);
            hv.w = fmaxf(fmaf(di, a0.w + sf.w, b14.w), 0.f);
            hreg[rr] = hv;
            float p1 = hv.x * wr4.x + hv.y * wr4.y + hv.z * wr4.z + hv.w * wr4.w;
            float p2 = hv.x * wo4.x + hv.y * wo4.y + hv.z * wo4.z + hv.w * wo4.w;
            p1 += __shfl_xor(p1, 1); p1 += __shfl_xor(p1, 2);
            p2 += __shfl_xor(p2, 1); p2 += __shfl_xor(p2, 2);
            if (l == 0) { hw[n] = p1; hro[n] = p2; }
        }
    }
    __syncthreads();
#pragma unroll
    for (int rr = 0; rr < 4; rr++)
        if (nidx[rr] >= 0) *(float4*)(feat + fidx4(nidx[rr], l)) = hreg[rr];
    __syncthreads();

    // ---- score: scalar gather of hw ----
#pragma unroll
    for (int rr = 0; rr < 4; rr++) {
        int n = nidx[rr];
        if (n >= 0) {
            int c8 = cnt8l[n];
            const unsigned short* cp = cg + n * CSTRIDE;
            float sm = 0.f;
            for (int k = 0; k < c8; k += 4) {
                uint2 wv = *(const uint2*)(cp + k);
                int s = (l == 0) ? (int)(wv.x & 0xFFFF) : (l == 1) ? (int)(wv.x >> 16)
                      : (l == 2) ? (int)(wv.y & 0xFFFF) : (int)(wv.y >> 16);
                sm += hw[s];
            }
            sm += __shfl_xor(sm, 1); sm += __shfl_xor(sm, 2);
            if (l == 0) sc[n] = tanhf(sm + hro[n] + brel);
        }
    }
    __syncthreads();

    // ---- top-K threshold: 1-level histogram + shuffle suffix scan ----
    unsigned int mykey = 0; int myb = -1;
    if (t < N_PER) { mykey = fkey(sc[t]); myb = (int)(mykey >> 22); }
    hist[t] = 0;
    __syncthreads();
    if (t < N_PER) atomicAdd(&hist[myb], 1);
    __syncthreads();
    {
        int cntb = hist[t];
        int v = cntb;
        for (int off = 1; off < 64; off <<= 1) {
            int u = __shfl_down(v, off, 64);
            if (lane + off < 64) v += u;
        }
        if (lane == 0) wtot[wid] = v;
        __syncthreads();
        if (wid == 0) {
            int wv2 = (lane < 16) ? wtot[lane] : 0;
            int sv = wv2;
            for (int off = 1; off < 16; off <<= 1) {
                int u = __shfl_down(sv, off, 64);
                if (lane + off < 64) sv += u;
            }
            if (lane < 16) wexc[lane] = sv - wv2;
        }
        __syncthreads();
        int S = v + wexc[wid];
        if (S >= K_TOP && S - cntb < K_TOP) { sh_b1 = t; sh_r1 = K_TOP - (S - cntb); }
    }
    __syncthreads();
    if (t < N_PER && myb == sh_b1) { int p = atomicAdd(&sh_len, 1); hist[p] = (int)mykey; }
    __syncthreads();
    {
        int L = sh_len, r1 = sh_r1;
        if (t < L) {
            unsigned int k0 = (unsigned int)hist[t];
            int gcnt = 0, ecnt = 0;
            for (int q2 = 0; q2 < L; q2++) {
                unsigned int kq = (unsigned int)hist[q2];
                gcnt += (kq > k0); ecnt += (kq == k0);
            }
            if (gcnt < r1 && r1 <= gcnt + ecnt) sh_thr = unfkey(k0);
        }
    }
    __syncthreads();
    float thr = sh_thr;

    // ---- mask (ties: lowest index first) ----
    {
        bool pred = (t < N_PER) && (sc[t] > thr);
        bool tied = (t < N_PER) && (sc[t] == thr);
        unsigned long long bal = __ballot(pred);
        if ((t & 63) == 0) atomicAdd(&sh_cntgt, (int)__popcll(bal));
        if (tied) atomicOr(&tiebits[t >> 5], 1u << (t & 31));
        __syncthreads();
        int need = K_TOP - sh_cntgt;
        if (t < N_PER) {
            float v = sc[t];
            float mm;
            if (v > thr) mm = 1.f;
            else if (v < thr) mm = 0.f;
            else {
                int w = t >> 5;
                int rank = __popc(tiebits[w] & ((1u << (t & 31)) - 1u));
                for (int ww = 0; ww < w; ww++) rank += __popc(tiebits[ww]);
                mm = (rank < need) ? 1.f : 0.f;
            }
            msk[t] = mm;
        }
    }
    __syncthreads();

    // ---- deg2 / dis2 / wsrc (scalar mask gather) ----
#pragma unroll
    for (int rr = 0; rr < 4; rr++) {
        int n = nidx[rr];
        if (n >= 0) {
            int c8 = cnt8l[n];
            const unsigned short* cp = cg + n * CSTRIDE;
            float sm = 0.f;
            for (int k = 0; k < c8; k += 4) {
                uint2 wv = *(const uint2*)(cp + k);
                int s = (l == 0) ? (int)(wv.x & 0xFFFF) : (l == 1) ? (int)(wv.x >> 16)
                      : (l == 2) ? (int)(wv.y & 0xFFFF) : (int)(wv.y >> 16);
                sm += msk[s];
            }
            sm += __shfl_xor(sm, 1); sm += __shfl_xor(sm, 2);
            if (l == 0) {
                float d2 = msk[n] * (sm + 1.f);
                float di = (d2 > 0.f) ? rsqrtf(d2) : 0.f;
                dis2a[n] = di;
                wsrc[n] = sc[n] * msk[n] * di;
            }
        }
    }
    __syncthreads();

    // ---- fold wsrc into features: feat2 = h * wsrc ----
    for (int i = t; i < N_PER * 4; i += 1024) {
        int n = i >> 2, q = i & 3;
        float w = wsrc[n];
        float4* p = (float4*)(feat + fidx4(n, q));
        float4 v = *p;
        v.x *= w; v.y *= w; v.z *= w; v.w *= w;
        *p = v;
    }
    __syncthreads();

    // ---- conv2 pre-aggregation ----
    float4 preg[4];
#pragma unroll
    for (int rr = 0; rr < 4; rr++) {
        int n = nidx[rr];
        if (n >= 0) {
            float di = dis2a[n];
            float4 pv = {0,0,0,0};
            if (di != 0.f) {
                int c8 = cnt8l[n];
                const unsigned short* cp = cg + n * CSTRIDE;
                float4 a0 = {0,0,0,0}, a1 = a0, a2 = a0, a3 = a0;
                for (int k = 0; k < c8; k += 4) {
                    uint2 wv = *(const uint2*)(cp + k);
                    add4(a0, *(const float4*)(feat + fidx4((int)(wv.x & 0xFFFF), l)));
                    add4(a1, *(const float4*)(feat + fidx4((int)(wv.x >> 16), l)));
                    add4(a2, *(const float4*)(feat + fidx4((int)(wv.y & 0xFFFF), l)));
                    add4(a3, *(const float4*)(feat + fidx4((int)(wv.y >> 16), l)));
                }
                add4(a0, a1); add4(a2, a3); add4(a0, a2);
                float4 sf = *(const float4*)(feat + fidx4(n, l));
                pv.x = di * (a0.x + sf.x);
                pv.y = di * (a0.y + sf.y);
                pv.z = di * (a0.z + sf.z);
                pv.w = di * (a0.w + sf.w);
            }
            preg[rr] = pv;
        }
    }
    __syncthreads();
#pragma unroll
    for (int rr = 0; rr < 4; rr++)
        if (nidx[rr] >= 0) *(float4*)(feat + fidx4(nidx[rr], l)) = preg[rr];
    __syncthreads();

    // ---- pre -> bf16 logical layout ----
    for (int i = t; i < N_PER * 8; i += 1024) {
        int n = i >> 3, cp2 = (i & 7) * 2;
        int phys = n * 16 + ((cp2 + 4 * ((n >> 1) & 3)) & 15);
        float2 v = *(const float2*)(feat + phys);
        unsigned int pk = (unsigned int)f2bf(v.x) | ((unsigned int)f2bf(v.y) << 16);
        ((unsigned int*)fbf)[i] = pk;
    }
    __syncthreads();

    // ---- final MFMA + relu + masked mean-pool ----
    {
        int q = lane >> 4, fl = lane & 15;
        int half = wid >> 3, wcol = wid & 7;
        int c0 = 32 * wcol + fl, c1 = c0 + 16;
        float b2f0 = b2[c0], b2f1 = b2[c1];
        short8 bfrag0 = {0,0,0,0,0,0,0,0}, bfrag1 = bfrag0;
        if (q < 2) {
            bfrag0 = *(const short8*)(w2t + c0 * F_MID + q * 8);
            bfrag1 = *(const short8*)(w2t + c1 * F_MID + q * 8);
        }
        floatx4 zero = {0.f, 0.f, 0.f, 0.f};
        float acc0 = 0.f, acc1 = 0.f;
        int t0 = half ? 32 : 0, t1 = half ? 63 : 32;
        for (int tile = t0; tile < t1; tile++) {
            short8 afrag = {0,0,0,0,0,0,0,0};
            int na = tile * 16 + fl;
            if (q < 2 && na < N_PER)
                afrag = *(const short8*)(fbf + na * F_MID + q * 8);
            floatx4 d0 = __builtin_amdgcn_mfma_f32_16x16x32_bf16(afrag, bfrag0, zero, 0, 0, 0);
            floatx4 d1 = __builtin_amdgcn_mfma_f32_16x16x32_bf16(afrag, bfrag1, zero, 0, 0, 0);
#pragma unroll
            for (int r = 0; r < 4; r++) {
                int nd = tile * 16 + q * 4 + r;
                if (nd < N_PER) {
                    float m = msk[nd];
                    acc0 += m * fmaxf(d0[r] + b2f0, 0.f);
                    acc1 += m * fmaxf(d1[r] + b2f1, 0.f);
                }
            }
        }
        acc0 += __shfl_xor(acc0, 16); acc0 += __shfl_xor(acc0, 32);
        acc1 += __shfl_xor(acc1, 16); acc1 += __shfl_xor(acc1, 32);
        if (half == 0 && lane < 16) { partial[c0] = acc0; partial[c1] = acc1; }
        __syncthreads();
        if (half == 1 && lane < 16) {
            out[g * F_OUT + c0] = (partial[c0] + acc0) * (1.0f / (float)K_TOP);
            out[g * F_OUT + c1] = (partial[c1] + acc1) * (1.0f / (float)K_TOP);
        }
    }
}

extern "C" void kernel_launch(void* const* d_in, const int* in_sizes, int n_in,
                              void* d_out, int out_size, void* d_ws, size_t ws_size,
                              hipStream_t stream) {
    const float* x      = (const float*)d_in[0];
    const int*   ei     = (const int*)d_in[1];
    const float* W1     = (const float*)d_in[3];
    const float* b1     = (const float*)d_in[4];
    const float* w_rel  = (const float*)d_in[5];
    const float* b_rel  = (const float*)d_in[6];
    const float* w_root = (const float*)d_in[7];
    const float* W2     = (const float*)d_in[8];
    const float* b2     = (const float*)d_in[9];
    float* out = (float*)d_out;

    char* ws = (char*)d_ws;
    size_t o = 0;
    unsigned short* csr = (unsigned short*)(ws + o); o += (size_t)NG * N_PER * CSTRIDE * sizeof(unsigned short);
    int*   cntG  = (int*)(ws + o);   o += (size_t)N_NODES * sizeof(int);
    float* dis1G = (float*)(ws + o); o += (size_t)N_NODES * sizeof(float);
    float* xw1   = (float*)(ws + o); o += (size_t)N_NODES * F_MID * sizeof(float);

    k_front<<<NG + GEMM_BLOCKS, 1024, 0, stream>>>(x, W1, ei, csr, cntG, dis1G, xw1);
    k_mega<<<NG, 1024, 0, stream>>>(csr, cntG, dis1G, xw1,
                                    b1, w_rel, b_rel, w_root, W2, b2, out);
}

// Round 8
// 241.503 us; speedup vs baseline: 1.0222x; 1.0222x over previous
//
#include <hip/hip_runtime.h>
#include <math.h>

#define N_NODES 100000
#define NG 100
#define N_PER 1000
#define N_EDGES 3200000
#define EPG 32000
#define EPG4 8000
#define CSR_G 36000         // compact CSR shorts per graph (32000 + up to 3*1000 pad, < 36000)
#define K_TOP 800
#define F_IN 128
#define F_MID 16
#define F_OUT 256
#define SENT 1000
#define GEMM_ROWS 256
#define GEMM_BLOCKS ((N_NODES + GEMM_ROWS - 1) / GEMM_ROWS)

typedef __attribute__((ext_vector_type(8))) short short8;
typedef __attribute__((ext_vector_type(4))) float floatx4;

__device__ __forceinline__ unsigned short f2bf(float x) {
    union { float f; unsigned int u; } c; c.f = x;
    unsigned int u = c.u;
    u = u + 0x7FFF + ((u >> 16) & 1);
    return (unsigned short)(u >> 16);
}
__device__ __forceinline__ float bf2f(unsigned short h) {
    return __uint_as_float(((unsigned int)h) << 16);
}
__device__ __forceinline__ void add4(float4& a, const float4 b) {
    a.x += b.x; a.y += b.y; a.z += b.z; a.w += b.w;
}
__device__ __forceinline__ int fidx4(int s, int l) {   // bank-conflict swizzle
    return s * 16 + ((4 * (l + ((s >> 1) & 3))) & 15);
}
__device__ __forceinline__ unsigned int fkey(float f) {  // order-preserving asc
    unsigned int u = __float_as_uint(f);
    return (u & 0x80000000u) ? ~u : (u | 0x80000000u);
}
__device__ __forceinline__ float unfkey(unsigned int k) {
    return __uint_as_float((k & 0x80000000u) ? (k & 0x7FFFFFFFu) : ~k);
}

// ============ kernel 1: CSR blocks (compact, c4 pad) + MFMA GEMM1 ============
__global__ __launch_bounds__(1024) void k_front(const float* __restrict__ x,
    const float* __restrict__ W1, const int* __restrict__ ei,
    unsigned short* __restrict__ csr, int* __restrict__ cnt4G, int* __restrict__ rsG,
    float* __restrict__ dis1G, float* __restrict__ xw1)
{
    __shared__ __align__(16) char smem[16640];
    int b = blockIdx.x, t = threadIdx.x;
    if (b < NG) {
        // ---- CSR build: count, scan, scatter (compact, rows padded to mult-of-4) ----
        int* cnts = (int*)smem;            // 1000
        int* cur  = (int*)(smem + 4000);   // 1000
        int* rs   = (int*)(smem + 8000);   // 1000
        int* scan = (int*)(smem + 12000);  // 1024
        int g = b, ebase = g * EPG, nbase = g * N_PER;
        const int4* dst4 = (const int4*)(ei + N_EDGES + ebase);
        const int4* src4 = (const int4*)(ei + ebase);
        if (t < N_PER) { cnts[t] = 0; cur[t] = 0; }
        __syncthreads();
        for (int i = t; i < EPG4; i += 1024) {
            int4 d = dst4[i];
            atomicAdd(&cnts[d.x - nbase], 1);
            atomicAdd(&cnts[d.y - nbase], 1);
            atomicAdd(&cnts[d.z - nbase], 1);
            atomicAdd(&cnts[d.w - nbase], 1);
        }
        __syncthreads();
        int c = (t < N_PER) ? cnts[t] : 0;
        int c4 = (c + 3) & ~3;
        scan[t] = c4;
        __syncthreads();
        for (int dd = 1; dd < 1024; dd <<= 1) {
            int v = (t >= dd) ? scan[t - dd] : 0;
            __syncthreads();
            scan[t] += v;
            __syncthreads();
        }
        int exc = scan[t] - c4;
        unsigned short* cg = csr + (size_t)g * CSR_G;
        if (t < N_PER) {
            rs[t] = exc; rsG[nbase + t] = exc; cnt4G[nbase + t] = c4;
            dis1G[nbase + t] = rsqrtf((float)c + 1.0f);
            for (int q = c; q < c4; q++) cg[exc + q] = (unsigned short)SENT;
        }
        __syncthreads();
        for (int i = t; i < EPG4; i += 1024) {
            int4 s4 = src4[i]; int4 d4 = dst4[i];
            int dl, p;
            dl = d4.x - nbase; p = rs[dl] + atomicAdd(&cur[dl], 1); cg[p] = (unsigned short)(s4.x - nbase);
            dl = d4.y - nbase; p = rs[dl] + atomicAdd(&cur[dl], 1); cg[p] = (unsigned short)(s4.y - nbase);
            dl = d4.z - nbase; p = rs[dl] + atomicAdd(&cur[dl], 1); cg[p] = (unsigned short)(s4.z - nbase);
            dl = d4.w - nbase; p = rs[dl] + atomicAdd(&cur[dl], 1); cg[p] = (unsigned short)(s4.w - nbase);
        }
    } else {
        // ---- GEMM1 tile: 256 rows, MFMA bf16x3 split ----
        unsigned short* bTh = (unsigned short*)smem;          // [16][128]
        unsigned short* bTl = (unsigned short*)(smem + 4096); // [16][128]
        for (int i = t; i < F_IN * F_MID; i += 1024) {
            int k = i >> 4, n = i & 15;
            float w = W1[i];
            unsigned short hh = f2bf(w);
            bTh[n * 128 + k] = hh;
            bTl[n * 128 + k] = f2bf(w - bf2f(hh));
        }
        __syncthreads();
        int wave = t >> 6, lane = t & 63;
        int m = lane & 15, q = lane >> 4;
        long rbase = (long)(b - NG) * GEMM_ROWS + wave * 16;
        long arow = rbase + m;
        const float* xr = x + ((arow < N_NODES) ? arow : (N_NODES - 1)) * F_IN;
        short8 ah[4], al[4], bh[4], bl[4];
#pragma unroll
        for (int c = 0; c < 4; c++) {
            float4 v0 = *(const float4*)(xr + 32 * c + 8 * q);
            float4 v1 = *(const float4*)(xr + 32 * c + 8 * q + 4);
            float vv[8] = {v0.x, v0.y, v0.z, v0.w, v1.x, v1.y, v1.z, v1.w};
            short8 h8, l8;
#pragma unroll
            for (int i = 0; i < 8; i++) {
                unsigned short hh = f2bf(vv[i]);
                h8[i] = (short)hh;
                l8[i] = (short)f2bf(vv[i] - bf2f(hh));
            }
            ah[c] = h8; al[c] = l8;
            bh[c] = *(const short8*)(bTh + m * 128 + 32 * c + 8 * q);
            bl[c] = *(const short8*)(bTl + m * 128 + 32 * c + 8 * q);
        }
        floatx4 acc = {0.f, 0.f, 0.f, 0.f};
#pragma unroll
        for (int c = 0; c < 4; c++) {
            acc = __builtin_amdgcn_mfma_f32_16x16x32_bf16(ah[c], bh[c], acc, 0, 0, 0);
            acc = __builtin_amdgcn_mfma_f32_16x16x32_bf16(al[c], bh[c], acc, 0, 0, 0);
            acc = __builtin_amdgcn_mfma_f32_16x16x32_bf16(ah[c], bl[c], acc, 0, 0, 0);
        }
#pragma unroll
        for (int r = 0; r < 4; r++) {
            long orow = rbase + q * 4 + r;
            if (orow < N_NODES) xw1[orow * F_MID + m] = acc[r];
        }
    }
}

// ============ kernel 2: per-graph phases (round-5 gather shape + L2 prefetch) ============
__global__ __launch_bounds__(1024) void k_mega(const unsigned short* __restrict__ csr,
    const int* __restrict__ cnt4G, const int* __restrict__ rsG,
    const float* __restrict__ dis1G, const float* __restrict__ xw1,
    const float* __restrict__ b1, const float* __restrict__ w_rel,
    const float* __restrict__ b_rel, const float* __restrict__ w_root,
    const float* __restrict__ W2, const float* __restrict__ b2,
    float* __restrict__ out)
{
    __shared__ __align__(16) float feat[(N_PER + 1) * F_MID];
    __shared__ __align__(16) unsigned short fbf[N_PER * F_MID];
    __shared__ __align__(16) unsigned short w2t[F_OUT * F_MID];
    __shared__ float sc[N_PER];
    __shared__ float msk[N_PER + 1];
    __shared__ float wsrc[N_PER + 1];
    __shared__ float hw[N_PER + 1];
    __shared__ float hro[N_PER];
    __shared__ float dis2a[N_PER];
    __shared__ float dis1l[N_PER];
    __shared__ int cnt4l[N_PER];
    __shared__ int rsl[N_PER];
    __shared__ int hist[1024];
    __shared__ float partial[F_OUT];
    __shared__ int wtot[16], wexc[16];
    __shared__ unsigned int tiebits[32];
    __shared__ int sh_b1, sh_r1, sh_len, sh_cntgt;
    __shared__ float sh_thr;

    int t = threadIdx.x, g = blockIdx.x;
    int nbase = g * N_PER;
    const unsigned short* cg = csr + (size_t)g * CSR_G;
    int grp = t >> 2, l = t & 3;
    int lane = t & 63, wid = t >> 6;

    // ---- L2 prefetch of this graph's CSR window (contiguous, overlaps staging) ----
    {
        const uint4* pf = (const uint4*)cg;   // CSR_G*2/16 = 4500 uint4
        unsigned int acc = 0;
        for (int i = t; i < 4500; i += 1024) acc |= pf[i].x;
        asm volatile("" :: "v"(acc));   // sink: keep the loads
    }

    if (t < N_PER) { cnt4l[t] = cnt4G[nbase + t]; rsl[t] = rsG[nbase + t]; dis1l[t] = dis1G[nbase + t]; }
    if (t == 0) { sh_cntgt = 0; sh_len = 0; }
    if (t < 32) tiebits[t] = 0;
    for (int i = t; i < F_OUT * F_MID; i += 1024) {
        int f = i >> 4, jj = i & 15;
        w2t[i] = f2bf(W2[jj * F_OUT + f]);
    }
    __syncthreads();

    // ---- stage feat = xw1 * dis1 (swizzled); sentinel row zero ----
    {
        const float4* xsrc = (const float4*)(xw1 + (size_t)nbase * F_MID);
        for (int i = t; i < N_PER * 4; i += 1024) {
            int n = i >> 2, q = i & 3;
            float4 v = xsrc[i];
            float d = dis1l[n];
            v.x *= d; v.y *= d; v.z *= d; v.w *= d;
            *(float4*)(feat + fidx4(n, q)) = v;
        }
        if (t < 4) { float4 z = {0.f, 0.f, 0.f, 0.f}; *(float4*)(feat + fidx4(SENT, t)) = z; }
        if (t == 0) { hw[SENT] = 0.f; msk[SENT] = 0.f; wsrc[SENT] = 0.f; }
    }
    __syncthreads();

    float4 b14 = *(const float4*)(b1 + 4 * l);
    float4 wr4 = *(const float4*)(w_rel + 4 * l);
    float4 wo4 = *(const float4*)(w_root + 4 * l);
    float brel = b_rel[0];

    // ---- conv1 aggregation + relu -> hreg; fused hw/hro readout ----
    float4 hreg[4];
#pragma unroll
    for (int rr = 0; rr < 4; rr++) {
        int n = grp + 256 * rr;
        if (n < N_PER) {
            int c4 = cnt4l[n];
            const unsigned short* cp = cg + rsl[n];
            float4 a0 = {0,0,0,0}, a1 = a0, a2 = a0, a3 = a0;
            for (int k = 0; k < c4; k += 4) {
                uint2 wv = *(const uint2*)(cp + k);
                add4(a0, *(const float4*)(feat + fidx4((int)(wv.x & 0xFFFF), l)));
                add4(a1, *(const float4*)(feat + fidx4((int)(wv.x >> 16), l)));
                add4(a2, *(const float4*)(feat + fidx4((int)(wv.y & 0xFFFF), l)));
                add4(a3, *(const float4*)(feat + fidx4((int)(wv.y >> 16), l)));
            }
            add4(a0, a1); add4(a2, a3); add4(a0, a2);
            float4 sf = *(const float4*)(feat + fidx4(n, l));
            float di = dis1l[n];
            float4 hv;
            hv.x = fmaxf(fmaf(di, a0.x + sf.x, b14.x), 0.f);
            hv.y = fmaxf(fmaf(di, a0.y + sf.y, b14.y), 0.f);
            hv.z = fmaxf(fmaf(di, a0.z + sf.z, b14.z), 0.f);
            hv.w = fmaxf(fmaf(di, a0.w + sf.w, b14.w), 0.f);
            hreg[rr] = hv;
            float p1 = hv.x * wr4.x + hv.y * wr4.y + hv.z * wr4.z + hv.w * wr4.w;
            float p2 = hv.x * wo4.x + hv.y * wo4.y + hv.z * wo4.z + hv.w * wo4.w;
            p1 += __shfl_xor(p1, 1); p1 += __shfl_xor(p1, 2);
            p2 += __shfl_xor(p2, 1); p2 += __shfl_xor(p2, 2);
            if (l == 0) { hw[n] = p1; hro[n] = p2; }
        }
    }
    __syncthreads();
#pragma unroll
    for (int rr = 0; rr < 4; rr++) {
        int n = grp + 256 * rr;
        if (n < N_PER) *(float4*)(feat + fidx4(n, l)) = hreg[rr];
    }
    __syncthreads();

    // ---- score: scalar gather of hw ----
#pragma unroll
    for (int rr = 0; rr < 4; rr++) {
        int n = grp + 256 * rr;
        if (n < N_PER) {
            int c4 = cnt4l[n];
            const unsigned short* cp = cg + rsl[n];
            float sm = 0.f;
            for (int k = 0; k < c4; k += 4) {
                uint2 wv = *(const uint2*)(cp + k);
                int s = (l == 0) ? (int)(wv.x & 0xFFFF) : (l == 1) ? (int)(wv.x >> 16)
                      : (l == 2) ? (int)(wv.y & 0xFFFF) : (int)(wv.y >> 16);
                sm += hw[s];
            }
            sm += __shfl_xor(sm, 1); sm += __shfl_xor(sm, 2);
            if (l == 0) sc[n] = tanhf(sm + hro[n] + brel);
        }
    }
    __syncthreads();

    // ---- top-K threshold: 1-level histogram + shuffle suffix scan ----
    unsigned int mykey = 0; int myb = -1;
    if (t < N_PER) { mykey = fkey(sc[t]); myb = (int)(mykey >> 22); }
    hist[t] = 0;
    __syncthreads();
    if (t < N_PER) atomicAdd(&hist[myb], 1);
    __syncthreads();
    {
        int cntb = hist[t];
        int v = cntb;
        for (int off = 1; off < 64; off <<= 1) {
            int u = __shfl_down(v, off, 64);
            if (lane + off < 64) v += u;
        }
        if (lane == 0) wtot[wid] = v;
        __syncthreads();
        if (wid == 0) {
            int wv2 = (lane < 16) ? wtot[lane] : 0;
            int sv = wv2;
            for (int off = 1; off < 16; off <<= 1) {
                int u = __shfl_down(sv, off, 64);
                if (lane + off < 64) sv += u;
            }
            if (lane < 16) wexc[lane] = sv - wv2;
        }
        __syncthreads();
        int S = v + wexc[wid];
        if (S >= K_TOP && S - cntb < K_TOP) { sh_b1 = t; sh_r1 = K_TOP - (S - cntb); }
    }
    __syncthreads();
    if (t < N_PER && myb == sh_b1) { int p = atomicAdd(&sh_len, 1); hist[p] = (int)mykey; }
    __syncthreads();
    {
        int L = sh_len, r1 = sh_r1;
        if (t < L) {
            unsigned int k0 = (unsigned int)hist[t];
            int gcnt = 0, ecnt = 0;
            for (int q2 = 0; q2 < L; q2++) {
                unsigned int kq = (unsigned int)hist[q2];
                gcnt += (kq > k0); ecnt += (kq == k0);
            }
            if (gcnt < r1 && r1 <= gcnt + ecnt) sh_thr = unfkey(k0);
        }
    }
    __syncthreads();
    float thr = sh_thr;

    // ---- mask (ties: lowest index first) ----
    {
        bool pred = (t < N_PER) && (sc[t] > thr);
        bool tied = (t < N_PER) && (sc[t] == thr);
        unsigned long long bal = __ballot(pred);
        if ((t & 63) == 0) atomicAdd(&sh_cntgt, (int)__popcll(bal));
        if (tied) atomicOr(&tiebits[t >> 5], 1u << (t & 31));
        __syncthreads();
        int need = K_TOP - sh_cntgt;
        if (t < N_PER) {
            float v = sc[t];
            float mm;
            if (v > thr) mm = 1.f;
            else if (v < thr) mm = 0.f;
            else {
                int w = t >> 5;
                int rank = __popc(tiebits[w] & ((1u << (t & 31)) - 1u));
                for (int ww = 0; ww < w; ww++) rank += __popc(tiebits[ww]);
                mm = (rank < need) ? 1.f : 0.f;
            }
            msk[t] = mm;
        }
    }
    __syncthreads();

    // ---- deg2 / dis2 / wsrc (scalar mask gather) ----
#pragma unroll
    for (int rr = 0; rr < 4; rr++) {
        int n = grp + 256 * rr;
        if (n < N_PER) {
            int c4 = cnt4l[n];
            const unsigned short* cp = cg + rsl[n];
            float sm = 0.f;
            for (int k = 0; k < c4; k += 4) {
                uint2 wv = *(const uint2*)(cp + k);
                int s = (l == 0) ? (int)(wv.x & 0xFFFF) : (l == 1) ? (int)(wv.x >> 16)
                      : (l == 2) ? (int)(wv.y & 0xFFFF) : (int)(wv.y >> 16);
                sm += msk[s];
            }
            sm += __shfl_xor(sm, 1); sm += __shfl_xor(sm, 2);
            if (l == 0) {
                float d2 = msk[n] * (sm + 1.f);
                float di = (d2 > 0.f) ? rsqrtf(d2) : 0.f;
                dis2a[n] = di;
                wsrc[n] = sc[n] * msk[n] * di;
            }
        }
    }
    __syncthreads();

    // ---- fold wsrc into features: feat2 = h * wsrc ----
    for (int i = t; i < N_PER * 4; i += 1024) {
        int n = i >> 2, q = i & 3;
        float w = wsrc[n];
        float4* p = (float4*)(feat + fidx4(n, q));
        float4 v = *p;
        v.x *= w; v.y *= w; v.z *= w; v.w *= w;
        *p = v;
    }
    __syncthreads();

    // ---- conv2 pre-aggregation ----
    float4 preg[4];
#pragma unroll
    for (int rr = 0; rr < 4; rr++) {
        int n = grp + 256 * rr;
        if (n < N_PER) {
            float di = dis2a[n];
            float4 pv = {0,0,0,0};
            if (di != 0.f) {
                int c4 = cnt4l[n];
                const unsigned short* cp = cg + rsl[n];
                float4 a0 = {0,0,0,0}, a1 = a0, a2 = a0, a3 = a0;
                for (int k = 0; k < c4; k += 4) {
                    uint2 wv = *(const uint2*)(cp + k);
                    add4(a0, *(const float4*)(feat + fidx4((int)(wv.x & 0xFFFF), l)));
                    add4(a1, *(const float4*)(feat + fidx4((int)(wv.x >> 16), l)));
                    add4(a2, *(const float4*)(feat + fidx4((int)(wv.y & 0xFFFF), l)));
                    add4(a3, *(const float4*)(feat + fidx4((int)(wv.y >> 16), l)));
                }
                add4(a0, a1); add4(a2, a3); add4(a0, a2);
                float4 sf = *(const float4*)(feat + fidx4(n, l));
                pv.x = di * (a0.x + sf.x);
                pv.y = di * (a0.y + sf.y);
                pv.z = di * (a0.z + sf.z);
                pv.w = di * (a0.w + sf.w);
            }
            preg[rr] = pv;
        }
    }
    __syncthreads();
#pragma unroll
    for (int rr = 0; rr < 4; rr++) {
        int n = grp + 256 * rr;
        if (n < N_PER) *(float4*)(feat + fidx4(n, l)) = preg[rr];
    }
    __syncthreads();

    // ---- pre -> bf16 logical layout ----
    for (int i = t; i < N_PER * 8; i += 1024) {
        int n = i >> 3, cp2 = (i & 7) * 2;
        int phys = n * 16 + ((cp2 + 4 * ((n >> 1) & 3)) & 15);
        float2 v = *(const float2*)(feat + phys);
        unsigned int pk = (unsigned int)f2bf(v.x) | ((unsigned int)f2bf(v.y) << 16);
        ((unsigned int*)fbf)[i] = pk;
    }
    __syncthreads();

    // ---- final MFMA + relu + masked mean-pool ----
    {
        int q = lane >> 4, fl = lane & 15;
        int half = wid >> 3, wcol = wid & 7;
        int c0 = 32 * wcol + fl, c1 = c0 + 16;
        float b2f0 = b2[c0], b2f1 = b2[c1];
        short8 bfrag0 = {0,0,0,0,0,0,0,0}, bfrag1 = bfrag0;
        if (q < 2) {
            bfrag0 = *(const short8*)(w2t + c0 * F_MID + q * 8);
            bfrag1 = *(const short8*)(w2t + c1 * F_MID + q * 8);
        }
        floatx4 zero = {0.f, 0.f, 0.f, 0.f};
        float acc0 = 0.f, acc1 = 0.f;
        int t0 = half ? 32 : 0, t1 = half ? 63 : 32;
        for (int tile = t0; tile < t1; tile++) {
            short8 afrag = {0,0,0,0,0,0,0,0};
            int na = tile * 16 + fl;
            if (q < 2 && na < N_PER)
                afrag = *(const short8*)(fbf + na * F_MID + q * 8);
            floatx4 d0 = __builtin_amdgcn_mfma_f32_16x16x32_bf16(afrag, bfrag0, zero, 0, 0, 0);
            floatx4 d1 = __builtin_amdgcn_mfma_f32_16x16x32_bf16(afrag, bfrag1, zero, 0, 0, 0);
#pragma unroll
            for (int r = 0; r < 4; r++) {
                int nd = tile * 16 + q * 4 + r;
                if (nd < N_PER) {
                    float m = msk[nd];
                    acc0 += m * fmaxf(d0[r] + b2f0, 0.f);
                    acc1 += m * fmaxf(d1[r] + b2f1, 0.f);
                }
            }
        }
        acc0 += __shfl_xor(acc0, 16); acc0 += __shfl_xor(acc0, 32);
        acc1 += __shfl_xor(acc1, 16); acc1 += __shfl_xor(acc1, 32);
        if (half == 0 && lane < 16) { partial[c0] = acc0; partial[c1] = acc1; }
        __syncthreads();
        if (half == 1 && lane < 16) {
            out[g * F_OUT + c0] = (partial[c0] + acc0) * (1.0f / (float)K_TOP);
            out[g * F_OUT + c1] = (partial[c1] + acc1) * (1.0f / (float)K_TOP);
        }
    }
}

extern "C" void kernel_launch(void* const* d_in, const int* in_sizes, int n_in,
                              void* d_out, int out_size, void* d_ws, size_t ws_size,
                              hipStream_t stream) {
    const float* x      = (const float*)d_in[0];
    const int*   ei     = (const int*)d_in[1];
    const float* W1     = (const float*)d_in[3];
    const float* b1     = (const float*)d_in[4];
    const float* w_rel  = (const float*)d_in[5];
    const float* b_rel  = (const float*)d_in[6];
    const float* w_root = (const float*)d_in[7];
    const float* W2     = (const float*)d_in[8];
    const float* b2     = (const float*)d_in[9];
    float* out = (float*)d_out;

    char* ws = (char*)d_ws;
    size_t o = 0;
    unsigned short* csr = (unsigned short*)(ws + o); o += (size_t)NG * CSR_G * sizeof(unsigned short);
    int*   cnt4G = (int*)(ws + o);   o += (size_t)N_NODES * sizeof(int);
    int*   rsG   = (int*)(ws + o);   o += (size_t)N_NODES * sizeof(int);
    float* dis1G = (float*)(ws + o); o += (size_t)N_NODES * sizeof(float);
    float* xw1   = (float*)(ws + o); o += (size_t)N_NODES * F_MID * sizeof(float);

    k_front<<<NG + GEMM_BLOCKS, 1024, 0, stream>>>(x, W1, ei, csr, cnt4G, rsG, dis1G, xw1);
    k_mega<<<NG, 1024, 0, stream>>>(csr, cnt4G, rsG, dis1G, xw1,
                                    b1, w_rel, b_rel, w_root, W2, b2, out);
}